// Round 2
// baseline (236.649 us; speedup 1.0000x reference)
//
#include <hip/hip_runtime.h>
#include <hip/hip_bf16.h>

// Problem constants (ExLlama q4: T=32, K=8192, N=28672, group=128)
// Harness dtype mapping: fp16 reference arrays are promoted to float32
// (only bf16/f32/int are native); output is float32.
#define T_TOK   32
#define KDIM    8192
#define NDIM    28672
#define NGRP    64        // K / 128
#define NZWORDS 3584      // N / 8

typedef _Float16 half8 __attribute__((ext_vector_type(8)));
typedef float    f32x4 __attribute__((ext_vector_type(4)));

// One wave handles 64 columns (4 n-tiles of 16) over one K-segment.
// MFMA 16x16x32 f16: A[m=lane&15][k=quad*8+j],
// B[k=quad*8+j][n=lane&15] -> one qweight dword per lane per n-tile.
// C/D: col(n)=lane&15, row(m)=quad*4+reg.
template<int NSEG, bool DIRECT>
__global__ __launch_bounds__(256, 4)
void exllama_gemm(const int*   __restrict__ qweight,
                  const int*   __restrict__ qzeros,
                  const float* __restrict__ scales,
                  const float* __restrict__ x,
                  const float* __restrict__ bias,
                  float*       __restrict__ ws,
                  float*       __restrict__ out)
{
    const int lane = threadIdx.x & 63;
    const int wav  = threadIdx.x >> 6;
    const int quad = lane >> 4;
    const int l16  = lane & 15;
    const int seg  = blockIdx.y;
    const int n0   = blockIdx.x * 256 + wav * 64;

    int nc[4];
    #pragma unroll
    for (int j = 0; j < 4; ++j) nc[j] = n0 + j * 16 + l16;

    f32x4 acc[4][2];
    #pragma unroll
    for (int j = 0; j < 4; ++j)
        #pragma unroll
        for (int m = 0; m < 2; ++m)
            acc[j][m] = (f32x4){0.f, 0.f, 0.f, 0.f};

    const int GPS = NGRP / NSEG;      // groups per K-segment
    const int g0  = seg * GPS;

    #pragma unroll 1
    for (int gi = 0; gi < GPS; ++gi) {
        const int g = g0 + gi;
        float sv[4], bv[4];
        #pragma unroll
        for (int j = 0; j < 4; ++j) {
            float s  = scales[g * NDIM + nc[j]];
            int   zw = qzeros[g * NZWORDS + (nc[j] >> 3)];
            int   z  = (zw >> ((nc[j] & 7) * 4)) & 15;
            sv[j] = s;
            bv[j] = -s * (float)(z + 1);   // w = q*s + bv
        }
        const int kwg = g * 16;           // qweight row base of this group
        #pragma unroll 2
        for (int c = 0; c < 4; ++c) {     // 4 chunks of 32 k per group
            const int kw    = kwg + c * 4 + quad;   // this lane's qweight row
            const int kbase = (kwg + c * 4) * 8;    // k at chunk start
            // A fragments: tokens l16 and l16+16, 8 consecutive k each
            half8 afrag[2];
            #pragma unroll
            for (int m = 0; m < 2; ++m) {
                const int t = l16 + 16 * m;
                const float* xp = x + (size_t)t * KDIM + kbase + quad * 8;
                f32x4 xlo = *(const f32x4*)(xp);
                f32x4 xhi = *(const f32x4*)(xp + 4);
                #pragma unroll
                for (int i = 0; i < 4; ++i) {
                    afrag[m][i]     = (_Float16)xlo[i];
                    afrag[m][i + 4] = (_Float16)xhi[i];
                }
            }
            #pragma unroll
            for (int j = 0; j < 4; ++j) {
                const unsigned w = (unsigned)qweight[(size_t)kw * NDIM + nc[j]];
                half8 bfrag;
                #pragma unroll
                for (int i = 0; i < 8; ++i) {
                    float q = (float)((w >> (4 * i)) & 15u);
                    bfrag[i] = (_Float16)__builtin_fmaf(q, sv[j], bv[j]);
                }
                acc[j][0] = __builtin_amdgcn_mfma_f32_16x16x32_f16(afrag[0], bfrag, acc[j][0], 0, 0, 0);
                acc[j][1] = __builtin_amdgcn_mfma_f32_16x16x32_f16(afrag[1], bfrag, acc[j][1], 0, 0, 0);
            }
        }
    }

    if (DIRECT) {
        #pragma unroll
        for (int j = 0; j < 4; ++j) {
            const int n  = n0 + j * 16 + l16;
            const float bb = bias[n];
            #pragma unroll
            for (int m = 0; m < 2; ++m)
                #pragma unroll
                for (int r = 0; r < 4; ++r) {
                    const int t = m * 16 + quad * 4 + r;
                    out[(size_t)t * NDIM + n] = acc[j][m][r] + bb;
                }
        }
    } else {
        float* wsp = ws + (size_t)seg * (T_TOK * NDIM);
        #pragma unroll
        for (int j = 0; j < 4; ++j) {
            const int n = n0 + j * 16 + l16;
            #pragma unroll
            for (int m = 0; m < 2; ++m)
                #pragma unroll
                for (int r = 0; r < 4; ++r) {
                    const int t = m * 16 + quad * 4 + r;
                    wsp[(size_t)t * NDIM + n] = acc[j][m][r];
                }
        }
    }
}

template<int NSEG>
__global__ __launch_bounds__(256)
void reduce_bias(const float* __restrict__ ws,
                 const float* __restrict__ bias,
                 float*       __restrict__ out)
{
    const int e = (blockIdx.x * 256 + threadIdx.x) * 4;  // 4 consecutive elems, same row
    const int n = e % NDIM;
    f32x4 sum = (f32x4){0.f, 0.f, 0.f, 0.f};
    #pragma unroll
    for (int s = 0; s < NSEG; ++s)
        sum += *(const f32x4*)(ws + (size_t)s * (T_TOK * NDIM) + e);
    f32x4 bb = *(const f32x4*)(bias + n);
    *(f32x4*)(out + e) = sum + bb;
}

extern "C" void kernel_launch(void* const* d_in, const int* in_sizes, int n_in,
                              void* d_out, int out_size, void* d_ws, size_t ws_size,
                              hipStream_t stream)
{
    const float* x  = (const float*)d_in[0];   // (32, 8192) f32 (fp16 promoted)
    const int* qweight = (const int*)d_in[1];  // (1024, 28672) i32
    const int* qzeros  = (const int*)d_in[2];  // (64, 3584) i32
    const float* sc = (const float*)d_in[3];   // (64, 28672) f32
    const float* bs = (const float*)d_in[4];   // (28672,) f32
    float* out      = (float*)d_out;           // (32, 28672) f32

    const size_t need = (size_t)8 * T_TOK * NDIM * sizeof(float);  // 29.4 MB partials
    if (ws_size >= need) {
        // 112 column-blocks x 8 K-segments, 4 waves/block (64 cols each)
        exllama_gemm<8, false><<<dim3(112, 8), 256, 0, stream>>>(
            qweight, qzeros, sc, x, bs, (float*)d_ws, out);
        reduce_bias<8><<<(T_TOK * NDIM) / (256 * 4), 256, 0, stream>>>(
            (const float*)d_ws, bs, out);
    } else {
        exllama_gemm<1, true><<<dim3(112, 1), 256, 0, stream>>>(
            qweight, qzeros, sc, x, bs, nullptr, out);
    }
}

// Round 3
// 235.809 us; speedup vs baseline: 1.0036x; 1.0036x over previous
//
#include <hip/hip_runtime.h>
#include <hip/hip_bf16.h>

// ExLlama q4: T=32, K=8192, N=28672, group=128.
// Harness promotes fp16 reference arrays to float32; output is float32.
#define T_TOK   32
#define KDIM    8192
#define NDIM    28672
#define NGRP    64        // K / 128
#define NZWORDS 3584      // N / 8

typedef _Float16 half8 __attribute__((ext_vector_type(8)));
typedef float    f32x4 __attribute__((ext_vector_type(4)));

// One wave: 64 columns (4 n-tiles of 16) over one K-segment.
// MFMA 16x16x32 f16: A[m=lane&15][k=quad*8+j], B[k=quad*8+j][n=lane&15]
// -> one qweight dword per lane per n-tile. C/D: col=lane&15, row=quad*4+reg.
// Latency hiding: register double-buffer at GROUP granularity (16 qweight
// dwords + scales/zeros per wave per group prefetched while computing the
// previous group). No barriers anywhere -> no vmcnt(0) drain.
template<int NSEG, bool DIRECT>
__global__ __launch_bounds__(256, 4)
void exllama_gemm(const int*   __restrict__ qweight,
                  const int*   __restrict__ qzeros,
                  const float* __restrict__ scales,
                  const float* __restrict__ x,
                  const float* __restrict__ bias,
                  float*       __restrict__ ws,
                  float*       __restrict__ out)
{
    const int lane = threadIdx.x & 63;
    const int wav  = threadIdx.x >> 6;
    const int quad = lane >> 4;
    const int l16  = lane & 15;
    const int seg  = blockIdx.y;
    const int n0   = blockIdx.x * 256 + wav * 64;

    int nc[4];
    #pragma unroll
    for (int j = 0; j < 4; ++j) nc[j] = n0 + j * 16 + l16;

    f32x4 acc[4][2];
    #pragma unroll
    for (int j = 0; j < 4; ++j)
        #pragma unroll
        for (int m = 0; m < 2; ++m)
            acc[j][m] = (f32x4){0.f, 0.f, 0.f, 0.f};

    const int GPS = NGRP / NSEG;
    const int g0  = seg * GPS;

    // x row bases for this lane's two tokens (l16 and l16+16), at quad's k sub-offset
    const float* xr0 = x + (size_t)l16 * KDIM + quad * 8;
    const float* xr1 = xr0 + (size_t)16 * KDIM;

    auto load_group = [&](int g, unsigned (&qw)[16], float (&sv)[4], float (&bv)[4]) {
        #pragma unroll
        for (int j = 0; j < 4; ++j) {
            float s  = scales[(size_t)g * NDIM + nc[j]];
            int   zw = qzeros[(size_t)g * NZWORDS + (nc[j] >> 3)];
            int   z  = (zw >> ((nc[j] & 7) * 4)) & 15;
            sv[j] = s;
            bv[j] = -s * (float)(z + 1);   // w = q*s + bv
        }
        const size_t rb = (size_t)(g * 16 + quad) * NDIM;
        #pragma unroll
        for (int c = 0; c < 4; ++c)
            #pragma unroll
            for (int j = 0; j < 4; ++j)
                qw[c * 4 + j] = (unsigned)qweight[rb + (size_t)(c * 4) * NDIM + nc[j]];
    };

    auto compute_group = [&](int g, const unsigned (&qw)[16],
                             const float (&sv)[4], const float (&bv)[4]) {
        #pragma unroll
        for (int c = 0; c < 4; ++c) {
            const int kofs = g * 128 + c * 32;   // + quad*8 already in xr
            f32x4 xa = *(const f32x4*)(xr0 + kofs);
            f32x4 xb = *(const f32x4*)(xr0 + kofs + 4);
            f32x4 xc = *(const f32x4*)(xr1 + kofs);
            f32x4 xd = *(const f32x4*)(xr1 + kofs + 4);
            half8 a0, a1;
            #pragma unroll
            for (int i = 0; i < 4; ++i) {
                a0[i]     = (_Float16)xa[i];
                a0[i + 4] = (_Float16)xb[i];
                a1[i]     = (_Float16)xc[i];
                a1[i + 4] = (_Float16)xd[i];
            }
            #pragma unroll
            for (int j = 0; j < 4; ++j) {
                const unsigned w = qw[c * 4 + j];
                half8 bf;
                #pragma unroll
                for (int i = 0; i < 8; ++i) {
                    float q = (float)((w >> (4 * i)) & 15u);
                    bf[i] = (_Float16)__builtin_fmaf(q, sv[j], bv[j]);
                }
                acc[j][0] = __builtin_amdgcn_mfma_f32_16x16x32_f16(a0, bf, acc[j][0], 0, 0, 0);
                acc[j][1] = __builtin_amdgcn_mfma_f32_16x16x32_f16(a1, bf, acc[j][1], 0, 0, 0);
            }
        }
    };

    unsigned qwA[16], qwB[16];
    float svA[4], bvA[4], svB[4], bvB[4];

    load_group(g0, qwA, svA, bvA);
    #pragma unroll 1
    for (int gi = 0; gi < GPS; gi += 2) {      // GPS is even (8 or 64)
        load_group(g0 + gi + 1, qwB, svB, bvB);
        compute_group(g0 + gi, qwA, svA, bvA);
        if (gi + 2 < GPS) load_group(g0 + gi + 2, qwA, svA, bvA);
        compute_group(g0 + gi + 1, qwB, svB, bvB);
    }

    if (DIRECT) {
        #pragma unroll
        for (int j = 0; j < 4; ++j) {
            const int n  = n0 + j * 16 + l16;
            const float bb = bias[n];
            #pragma unroll
            for (int m = 0; m < 2; ++m)
                #pragma unroll
                for (int r = 0; r < 4; ++r) {
                    const int t = m * 16 + quad * 4 + r;
                    out[(size_t)t * NDIM + n] = acc[j][m][r] + bb;
                }
        }
    } else {
        float* wsp = ws + (size_t)seg * (T_TOK * NDIM);
        #pragma unroll
        for (int j = 0; j < 4; ++j) {
            const int n = n0 + j * 16 + l16;
            #pragma unroll
            for (int m = 0; m < 2; ++m)
                #pragma unroll
                for (int r = 0; r < 4; ++r) {
                    const int t = m * 16 + quad * 4 + r;
                    wsp[(size_t)t * NDIM + n] = acc[j][m][r];
                }
        }
    }
}

template<int NSEG>
__global__ __launch_bounds__(256)
void reduce_bias(const float* __restrict__ ws,
                 const float* __restrict__ bias,
                 float*       __restrict__ out)
{
    const int e = (blockIdx.x * 256 + threadIdx.x) * 4;  // 4 consecutive elems, one row
    const int n = e % NDIM;
    f32x4 sum = (f32x4){0.f, 0.f, 0.f, 0.f};
    #pragma unroll
    for (int s = 0; s < NSEG; ++s)
        sum += *(const f32x4*)(ws + (size_t)s * (T_TOK * NDIM) + e);
    f32x4 bb = *(const f32x4*)(bias + n);
    *(f32x4*)(out + e) = sum + bb;
}

extern "C" void kernel_launch(void* const* d_in, const int* in_sizes, int n_in,
                              void* d_out, int out_size, void* d_ws, size_t ws_size,
                              hipStream_t stream)
{
    const float* x  = (const float*)d_in[0];   // (32, 8192) f32 (fp16 promoted)
    const int* qweight = (const int*)d_in[1];  // (1024, 28672) i32
    const int* qzeros  = (const int*)d_in[2];  // (64, 3584) i32
    const float* sc = (const float*)d_in[3];   // (64, 28672) f32
    const float* bs = (const float*)d_in[4];   // (28672,) f32
    float* out      = (float*)d_out;           // (32, 28672) f32

    const size_t need = (size_t)8 * T_TOK * NDIM * sizeof(float);  // 29.4 MB partials
    if (ws_size >= need) {
        exllama_gemm<8, false><<<dim3(112, 8), 256, 0, stream>>>(
            qweight, qzeros, sc, x, bs, (float*)d_ws, out);
        reduce_bias<8><<<(T_TOK * NDIM) / (256 * 4), 256, 0, stream>>>(
            (const float*)d_ws, bs, out);
    } else {
        exllama_gemm<1, true><<<dim3(112, 1), 256, 0, stream>>>(
            qweight, qzeros, sc, x, bs, nullptr, out);
    }
}

// Round 4
// 203.380 us; speedup vs baseline: 1.1636x; 1.1594x over previous
//
#include <hip/hip_runtime.h>

// ExLlama q4: T=32, K=8192, N=28672, group=128.
// Harness promotes fp16 reference arrays to float32; output is float32.
#define T_TOK   32
#define KDIM    8192
#define NDIM    28672
#define NGRP    64        // K / 128
#define NZWORDS 3584      // N / 8
#define NSEG    8         // K-segments (blockIdx.y)
#define SEGK    1024      // KDIM / NSEG
#define GPS     8         // groups per segment (SEGK / 128)
#define XROW    1032      // padded LDS row stride (fp16 elems): 1024 + 8

typedef _Float16 half8  __attribute__((ext_vector_type(8)));
typedef _Float16 half2v __attribute__((ext_vector_type(2)));
typedef float    f32x4  __attribute__((ext_vector_type(4)));
typedef unsigned uint4v __attribute__((ext_vector_type(4)));

// One wave: 64 columns (4 n-tiles of 16) over one K-segment.
// MFMA 16x16x32 f16: A[m=lane&15][k=quad*8+j], B[k=quad*8+j][n=lane&15],
// C/D: col=lane&15, row=quad*4+reg.
// Within each 8-k block, BOTH A (at LDS staging) and B (nibble pairs) use the
// k-permutation [0,4,1,5,2,6,3,7], so the MFMA dot product is unchanged.
// Dequant: pair = ((w>>4i)&0x000F000F)|0x64006400 -> fp16 (1024+q_i,1024+q_{i+4});
// b = (pair + (-(1025+z))) * s  via v_pk_add_f16 / v_pk_mul_f16 (integer part exact).
__global__ __launch_bounds__(256, 2)
void exllama_gemm_lds(const int*   __restrict__ qweight,
                      const int*   __restrict__ qzeros,
                      const float* __restrict__ scales,
                      const float* __restrict__ x,
                      float*       __restrict__ ws)
{
    __shared__ alignas(16) _Float16 xs[T_TOK * XROW];   // 66 KB

    const int tid  = threadIdx.x;
    const int lane = tid & 63;
    const int wav  = tid >> 6;
    const int quad = lane >> 4;
    const int l16  = lane & 15;
    const int seg  = blockIdx.y;
    const int n0   = blockIdx.x * 256 + wav * 64;

    // ---- stage x segment into LDS as fp16, pair-permuted ----
    {
        const int kseg0 = seg * SEGK;
        #pragma unroll
        for (int it = 0; it < (T_TOK * SEGK) / (256 * 8); ++it) {   // 16 iters
            const int e  = it * 2048 + tid * 8;
            const int t  = e >> 10;          // SEGK = 1024
            const int kl = e & 1023;
            const float* xp = x + (size_t)t * KDIM + kseg0 + kl;
            f32x4 lo = *(const f32x4*)xp;
            f32x4 hi = *(const f32x4*)(xp + 4);
            uint4v u;
            #pragma unroll
            for (int j = 0; j < 4; ++j) {
                unsigned a = (unsigned)__builtin_bit_cast(unsigned short, (_Float16)lo[j]);
                unsigned b = (unsigned)__builtin_bit_cast(unsigned short, (_Float16)hi[j]);
                u[j] = a | (b << 16);        // (k+j, k+j+4) pair
            }
            *(uint4v*)(xs + t * XROW + kl) = u;
        }
    }
    __syncthreads();

    int nc[4];
    #pragma unroll
    for (int j = 0; j < 4; ++j) nc[j] = n0 + j * 16 + l16;

    f32x4 acc[4][2];
    #pragma unroll
    for (int j = 0; j < 4; ++j)
        #pragma unroll
        for (int m = 0; m < 2; ++m)
            acc[j][m] = (f32x4){0.f, 0.f, 0.f, 0.f};

    const int g0 = seg * GPS;

    unsigned qw[2][16];
    half2v   sp[2][4], cp[2][4];

    auto load_group = [&](int g, int b) {
        #pragma unroll
        for (int j = 0; j < 4; ++j) {
            float s  = scales[(size_t)g * NDIM + nc[j]];
            int   zw = qzeros[(size_t)g * NZWORDS + (nc[j] >> 3)];
            int   z  = (zw >> ((nc[j] & 7) * 4)) & 15;
            _Float16 sh = (_Float16)s;
            _Float16 ch = (_Float16)(float)(-(1025 + z));
            sp[b][j] = (half2v){sh, sh};
            cp[b][j] = (half2v){ch, ch};
        }
        const size_t rb = (size_t)(g * 16 + quad) * NDIM;
        #pragma unroll
        for (int c = 0; c < 4; ++c)
            #pragma unroll
            for (int j = 0; j < 4; ++j)
                qw[b][c * 4 + j] = (unsigned)qweight[rb + (size_t)(c * 4) * NDIM + nc[j]];
    };

    auto compute_group = [&](int gi, int b) {
        #pragma unroll
        for (int c = 0; c < 4; ++c) {
            const int kloc = gi * 128 + c * 32 + quad * 8;
            half8 a0 = *(const half8*)(xs + l16 * XROW + kloc);
            half8 a1 = *(const half8*)(xs + (l16 + 16) * XROW + kloc);
            #pragma unroll
            for (int j = 0; j < 4; ++j) {
                const unsigned w = qw[b][c * 4 + j];
                uint4v bu;
                #pragma unroll
                for (int i = 0; i < 4; ++i) {
                    unsigned t = ((w >> (4 * i)) & 0x000F000Fu) | 0x64006400u;
                    half2v th = __builtin_bit_cast(half2v, t);
                    half2v r  = (th + cp[b][j]) * sp[b][j];
                    bu[i] = __builtin_bit_cast(unsigned, r);
                }
                half8 bf = __builtin_bit_cast(half8, bu);
                acc[j][0] = __builtin_amdgcn_mfma_f32_16x16x32_f16(a0, bf, acc[j][0], 0, 0, 0);
                acc[j][1] = __builtin_amdgcn_mfma_f32_16x16x32_f16(a1, bf, acc[j][1], 0, 0, 0);
            }
        }
    };

    load_group(g0, 0);
    #pragma unroll 1
    for (int gi = 0; gi < GPS; gi += 2) {
        load_group(g0 + gi + 1, 1);
        compute_group(gi, 0);
        if (gi + 2 < GPS) load_group(g0 + gi + 2, 0);
        compute_group(gi + 1, 1);
    }

    float* wsp = ws + (size_t)seg * (T_TOK * NDIM);
    #pragma unroll
    for (int j = 0; j < 4; ++j) {
        const int n = n0 + j * 16 + l16;
        #pragma unroll
        for (int m = 0; m < 2; ++m)
            #pragma unroll
            for (int r = 0; r < 4; ++r) {
                const int t = m * 16 + quad * 4 + r;
                wsp[(size_t)t * NDIM + n] = acc[j][m][r];
            }
    }
}

__global__ __launch_bounds__(256)
void reduce_bias(const float* __restrict__ ws,
                 const float* __restrict__ bias,
                 float*       __restrict__ out)
{
    const int e = (blockIdx.x * 256 + threadIdx.x) * 4;
    const int n = e % NDIM;
    f32x4 sum = (f32x4){0.f, 0.f, 0.f, 0.f};
    #pragma unroll
    for (int s = 0; s < NSEG; ++s)
        sum += *(const f32x4*)(ws + (size_t)s * (T_TOK * NDIM) + e);
    f32x4 bb = *(const f32x4*)(bias + n);
    *(f32x4*)(out + e) = sum + bb;
}

// Fallback (ws too small): direct, no LDS — correctness only.
__global__ __launch_bounds__(256)
void exllama_gemm_direct(const int*   __restrict__ qweight,
                         const int*   __restrict__ qzeros,
                         const float* __restrict__ scales,
                         const float* __restrict__ x,
                         const float* __restrict__ bias,
                         float*       __restrict__ out)
{
    const int lane = threadIdx.x & 63;
    const int wav  = threadIdx.x >> 6;
    const int quad = lane >> 4;
    const int l16  = lane & 15;
    const int n0   = blockIdx.x * 256 + wav * 64;

    int nc[4];
    #pragma unroll
    for (int j = 0; j < 4; ++j) nc[j] = n0 + j * 16 + l16;

    f32x4 acc[4][2];
    #pragma unroll
    for (int j = 0; j < 4; ++j)
        #pragma unroll
        for (int m = 0; m < 2; ++m)
            acc[j][m] = (f32x4){0.f, 0.f, 0.f, 0.f};

    #pragma unroll 1
    for (int g = 0; g < NGRP; ++g) {
        float sv[4], bv[4];
        #pragma unroll
        for (int j = 0; j < 4; ++j) {
            float s  = scales[(size_t)g * NDIM + nc[j]];
            int   zw = qzeros[(size_t)g * NZWORDS + (nc[j] >> 3)];
            int   z  = (zw >> ((nc[j] & 7) * 4)) & 15;
            sv[j] = s; bv[j] = -s * (float)(z + 1);
        }
        #pragma unroll
        for (int c = 0; c < 4; ++c) {
            const int kw    = g * 16 + c * 4 + quad;
            const int kbase = (g * 16 + c * 4) * 8;
            half8 a0, a1;
            #pragma unroll
            for (int m = 0; m < 2; ++m) {
                const float* xp = x + (size_t)(l16 + 16 * m) * KDIM + kbase + quad * 8;
                f32x4 xa = *(const f32x4*)xp;
                f32x4 xb = *(const f32x4*)(xp + 4);
                #pragma unroll
                for (int i = 0; i < 4; ++i) {
                    (m ? a1 : a0)[i]     = (_Float16)xa[i];
                    (m ? a1 : a0)[i + 4] = (_Float16)xb[i];
                }
            }
            #pragma unroll
            for (int j = 0; j < 4; ++j) {
                const unsigned w = (unsigned)qweight[(size_t)kw * NDIM + nc[j]];
                half8 bf;
                #pragma unroll
                for (int i = 0; i < 8; ++i)
                    bf[i] = (_Float16)__builtin_fmaf((float)((w >> (4 * i)) & 15u), sv[j], bv[j]);
                acc[j][0] = __builtin_amdgcn_mfma_f32_16x16x32_f16(a0, bf, acc[j][0], 0, 0, 0);
                acc[j][1] = __builtin_amdgcn_mfma_f32_16x16x32_f16(a1, bf, acc[j][1], 0, 0, 0);
            }
        }
    }
    #pragma unroll
    for (int j = 0; j < 4; ++j) {
        const int n = n0 + j * 16 + l16;
        const float bb = bias[n];
        #pragma unroll
        for (int m = 0; m < 2; ++m)
            #pragma unroll
            for (int r = 0; r < 4; ++r)
                out[(size_t)(m * 16 + quad * 4 + r) * NDIM + n] = acc[j][m][r] + bb;
    }
}

extern "C" void kernel_launch(void* const* d_in, const int* in_sizes, int n_in,
                              void* d_out, int out_size, void* d_ws, size_t ws_size,
                              hipStream_t stream)
{
    const float* x  = (const float*)d_in[0];   // (32, 8192) f32 (fp16 promoted)
    const int* qweight = (const int*)d_in[1];  // (1024, 28672) i32
    const int* qzeros  = (const int*)d_in[2];  // (64, 3584) i32
    const float* sc = (const float*)d_in[3];   // (64, 28672) f32
    const float* bs = (const float*)d_in[4];   // (28672,) f32
    float* out      = (float*)d_out;           // (32, 28672) f32

    const size_t need = (size_t)NSEG * T_TOK * NDIM * sizeof(float);  // 29.4 MB
    if (ws_size >= need) {
        exllama_gemm_lds<<<dim3(112, NSEG), 256, 0, stream>>>(
            qweight, qzeros, sc, x, (float*)d_ws);
        reduce_bias<<<(T_TOK * NDIM) / (256 * 4), 256, 0, stream>>>(
            (const float*)d_ws, bs, out);
    } else {
        exllama_gemm_direct<<<112, 256, 0, stream>>>(
            qweight, qzeros, sc, x, bs, out);
    }
}